// Round 11
// baseline (908.557 us; speedup 1.0000x reference)
//
#include <hip/hip_runtime.h>
#include <hip/hip_bf16.h>
#include <math.h>
#include <stdint.h>

// ---- problem constants ----
#define SEQ   4096
#define DIMM  2048
#define NH    32
#define NKV   8
#define HD    64
#define NSP   1100   // 300 vertical + 800 slash (duplicates kept)
#define NSPP  1152   // padded to multiple of 64

typedef __bf16 bf16x8 __attribute__((ext_vector_type(8)));
typedef float  f32x4  __attribute__((ext_vector_type(4)));

#define MODE_V 0
#define MODE_Q 1
#define MODE_O 2

// Split a run of 8 f32 into hi/lo bf16 fragments (hi+lo ~ f32 fidelity).
__device__ inline void split8(const float* __restrict__ p, bf16x8& h, bf16x8& l) {
#pragma unroll
    for (int i = 0; i < 8; ++i) {
        float v = p[i];
        __bf16 hv = (__bf16)v;
        h[i] = hv;
        l[i] = (__bf16)(v - (float)hv);
    }
}
// Load 4 consecutive elements as f32 from f32-or-bf16 memory.
__device__ inline f32x4 load4(const void* __restrict__ p, size_t idx, bool f) {
    if (f) return *(const f32x4*)((const float*)p + idx);
    const __bf16* b = (const __bf16*)p + idx;
    f32x4 v;
    v[0] = (float)b[0]; v[1] = (float)b[1]; v[2] = (float)b[2]; v[3] = (float)b[3];
    return v;
}
// Async global->LDS 16B copy (gfx950). LDS dest = wave-uniform base + lane*16.
__device__ __forceinline__ void gl_lds16(const __bf16* __restrict__ g, __bf16* l) {
    __builtin_amdgcn_global_load_lds(
        (const __attribute__((address_space(1))) void*)g,
        (__attribute__((address_space(3))) void*)l, 16, 0, 0);
}
// cos/sin fetch (f32-or-bf16 table)
__device__ __forceinline__ void cs_at(const void* fc, const void* fs, bool f,
                                      int t, int j, float& c, float& s) {
    if (f) {
        c = ((const float*)fc)[t * 32 + j];
        s = ((const float*)fs)[t * 32 + j];
    } else {
        c = (float)((const __bf16*)fc)[t * 32 + j];
        s = (float)((const __bf16*)fs)[t * 32 + j];
    }
}

// =====================================================================
// Input-dtype detection: flag=1 -> f32 inputs/outputs, flag=0 -> bf16.
// =====================================================================
__global__ __launch_bounds__(256) void detect_k(const void* __restrict__ x,
                                                int* __restrict__ flag) {
    const __bf16* p = (const __bf16*)x;
    int tid = threadIdx.x;
    bool bad = false;
    for (int i = 0; i < 16; ++i) {
        float v = fabsf((float)p[tid * 16 + i]);
        if (!(v <= 1e10f)) bad = true;    // catches huge AND NaN
    }
    unsigned long long m = __ballot(bad);
    __shared__ unsigned long long w[4];
    if ((tid & 63) == 0) w[tid >> 6] = m;
    __syncthreads();
    if (tid == 0) flag[0] = ((w[0] | w[1] | w[2] | w[3]) != 0ULL) ? 1 : 0;
}

// =====================================================================
// Tile transpose + convert body: out[c][r] = (bf16)in[r][c]
// =====================================================================
__device__ __forceinline__ void transpose_body(const void* __restrict__ in,
                                               __bf16* __restrict__ out,
                                               int R, int C, bool f,
                                               int cb, int rb) {
    __shared__ __bf16 tile[32][33];
    int tx = threadIdx.x & 31, ty = threadIdx.x >> 5;   // 32 x 8
    for (int i = 0; i < 32; i += 8) {
        size_t idx = (size_t)(rb + ty + i) * C + cb + tx;
        float v = f ? ((const float*)in)[idx] : (float)((const __bf16*)in)[idx];
        tile[ty + i][tx] = (__bf16)v;
    }
    __syncthreads();
    for (int i = 0; i < 32; i += 8)
        out[(size_t)(cb + ty + i) * R + rb + tx] = tile[tx][ty + i];
}

// Transpose with hi/lo split: oh/ol[c][r] = split(f32 in[r][c]).
// Same rounding as the old in-kernel split8 (bit-exact operands).
__device__ __forceinline__ void transpose_split_body(const void* __restrict__ in,
                                                     __bf16* __restrict__ oh,
                                                     __bf16* __restrict__ ol,
                                                     int R, int C, bool f,
                                                     int cb, int rb) {
    __shared__ float tf[32][33];
    int tx = threadIdx.x & 31, ty = threadIdx.x >> 5;   // 32 x 8
    for (int i = 0; i < 32; i += 8) {
        size_t idx = (size_t)(rb + ty + i) * C + cb + tx;
        tf[ty + i][tx] = f ? ((const float*)in)[idx] : (float)((const __bf16*)in)[idx];
    }
    __syncthreads();
    for (int i = 0; i < 32; i += 8) {
        float v = tf[tx][ty + i];
        __bf16 h = (__bf16)v;
        size_t o = (size_t)(cb + ty + i) * R + rb + tx;
        oh[o] = h;
        ol[o] = (__bf16)(v - (float)h);
    }
}

// =====================================================================
// Merged: convert x -> xbf (4096 blocks) + wk -> Wtk_h/Wtk_l transposed
// split (1024 blocks). Outputs disjoint from inputs -> safe co-resident.
// =====================================================================
__global__ __launch_bounds__(256) void convert_wkt_k(const void* __restrict__ x,
                                                     __bf16* __restrict__ xb,
                                                     const void* __restrict__ wk,
                                                     __bf16* __restrict__ Wtk_h,
                                                     __bf16* __restrict__ Wtk_l,
                                                     const int* __restrict__ flag) {
    int bid = blockIdx.x;
    bool f = (*flag != 0);
    if (bid < 4096) {
        int i0 = (bid * 256 + threadIdx.x) * 8;
        if (f) {
            const float* xf = (const float*)x;
            bf16x8 o;
            for (int i = 0; i < 8; ++i) o[i] = (__bf16)xf[i0 + i];
            *(bf16x8*)(xb + i0) = o;
        } else {
            *(bf16x8*)(xb + i0) = *(const bf16x8*)((const __bf16*)x + i0);
        }
    } else {
        int id = bid - 4096;                 // 1024 tiles: wk 2048x512
        int cb = (id >> 6) * 32, rb = (id & 63) * 32;
        transpose_split_body(wk, Wtk_h, Wtk_l, 2048, 512, f, cb, rb);
    }
}

// =====================================================================
// K-proj split GEMM: 32x128 tile, BK=64, PRE-SPLIT B (Wtk_h/l, NT bf16)
// staged via global_load_lds (linear, conflict-free); A f32-LDS
// (stride 68 -> <=2-way) + split8 on A only. MFMA chain per 32-chunk:
// al*bh, ah*bl, ah*bh in old order -> bit-exact with previous rounds.
// Epilogue: rope all rows, f32 out + bf16 Kb emit.
// =====================================================================
__device__ __forceinline__ void gemm_ksplit_body(const void* __restrict__ x,
                                                 const __bf16* __restrict__ Bh,
                                                 const __bf16* __restrict__ Bl,
                                                 float* __restrict__ C,
                                                 __bf16* __restrict__ Cb,
                                                 bool f, int bm, int bn,
                                                 const void* __restrict__ fc,
                                                 const void* __restrict__ fs,
                                                 char* smem) {
    const int K = DIMM, N = 512;
    float (*Asf)[68] = (float (*)[68])smem;            // 32*68*4 = 8704 B
    __bf16* Bsh = (__bf16*)(smem + 8704);              // 128*64*2 = 16384 B
    __bf16* Bsl = (__bf16*)(smem + 8704 + 16384);      // 16384 B (tot 41472)
    int tid = threadIdx.x, wave = tid >> 6, lane = tid & 63;
    int quad = lane >> 4, l16 = lane & 15;
    int wn = wave * 32;
    const f32x4 z4 = {0.f, 0.f, 0.f, 0.f};
    f32x4 acc[2][2];
    for (int a = 0; a < 2; ++a) for (int b = 0; b < 2; ++b) acc[a][b] = z4;
    int arow = tid >> 3, ac8 = (tid & 7) * 8;
    const __bf16* Bhb = Bh + (size_t)(bn * 128) * K;
    const __bf16* Blb = Bl + (size_t)(bn * 128) * K;
    for (int k0 = 0; k0 < K; k0 += 64) {
        f32x4 va0 = load4(x, (size_t)(bm * 32 + arow) * K + k0 + ac8, f);
        f32x4 va1 = load4(x, (size_t)(bm * 32 + arow) * K + k0 + ac8 + 4, f);
        *(f32x4*)&Asf[arow][ac8]     = va0;
        *(f32x4*)&Asf[arow][ac8 + 4] = va1;
#pragma unroll
        for (int it = 0; it < 4; ++it) {
            int ci = it * 256 + tid;
            int row = ci >> 3, c8 = (ci & 7) * 8;
            gl_lds16(Bhb + (size_t)row * K + k0 + c8, Bsh + ci * 8);
            gl_lds16(Blb + (size_t)row * K + k0 + c8, Bsl + ci * 8);
        }
        __syncthreads();
#pragma unroll
        for (int ks = 0; ks < 2; ++ks) {
            bf16x8 ah[2], al[2], bh[2], bl[2];
#pragma unroll
            for (int mt = 0; mt < 2; ++mt)
                split8(&Asf[mt * 16 + l16][ks * 32 + quad * 8], ah[mt], al[mt]);
#pragma unroll
            for (int nt = 0; nt < 2; ++nt) {
                bh[nt] = *(const bf16x8*)&Bsh[(wn + nt * 16 + l16) * 64 + ks * 32 + quad * 8];
                bl[nt] = *(const bf16x8*)&Bsl[(wn + nt * 16 + l16) * 64 + ks * 32 + quad * 8];
            }
#pragma unroll
            for (int mt = 0; mt < 2; ++mt)
#pragma unroll
                for (int nt = 0; nt < 2; ++nt) {
                    acc[mt][nt] = __builtin_amdgcn_mfma_f32_16x16x32_bf16(al[mt], bh[nt], acc[mt][nt], 0, 0, 0);
                    acc[mt][nt] = __builtin_amdgcn_mfma_f32_16x16x32_bf16(ah[mt], bl[nt], acc[mt][nt], 0, 0, 0);
                    acc[mt][nt] = __builtin_amdgcn_mfma_f32_16x16x32_bf16(ah[mt], bh[nt], acc[mt][nt], 0, 0, 0);
                }
        }
        __syncthreads();
    }
    for (int mt = 0; mt < 2; ++mt)
        for (int nt = 0; nt < 2; ++nt)
#pragma unroll
            for (int r = 0; r < 4; ++r) {
                int col = bn * 128 + wn + nt * 16 + l16;
                int t = bm * 32 + mt * 16 + quad * 4 + r;
                float v = acc[mt][nt][r];
                float pv = __shfl_xor(v, 1);
                int j = (col & 63) >> 1;
                float c, s;
                cs_at(fc, fs, f, t, j, c, s);
                float o = (lane & 1) ? (pv * s + v * c) : (v * c - pv * s);
                C[(size_t)t * N + col] = o;
                Cb[(size_t)t * N + col] = (__bf16)o;
            }
}

// =====================================================================
// Qe-proj split GEMM (old f32-staging body), 32x128 tile, rope t<64.
// Only 32 blocks (rows 0..63 — rows 64+ were never read downstream).
// =====================================================================
__device__ __forceinline__ void gemm_qesplit_body(const void* __restrict__ A,
                                                  const void* __restrict__ B,
                                                  float* __restrict__ C,
                                                  int N, bool f, int bm, int bn,
                                                  const void* __restrict__ fc,
                                                  const void* __restrict__ fs,
                                                  char* smem) {
    const int K = DIMM;
    float (*Asf)[36] = (float (*)[36])smem;              // 32*36*4 = 4608
    float (*Bsf)[36] = (float (*)[36])(smem + 4608);     // 128*36*4 = 18432
    int tid = threadIdx.x, wave = tid >> 6, lane = tid & 63;
    int quad = lane >> 4, l16 = lane & 15;
    int wn = wave * 32;
    const f32x4 z4 = {0.f, 0.f, 0.f, 0.f};
    f32x4 acc[2][2];
    for (int a = 0; a < 2; ++a) for (int b = 0; b < 2; ++b) acc[a][b] = z4;
    int arow = tid >> 3, acol = (tid & 7) * 4;
    for (int k0 = 0; k0 < K; k0 += 32) {
        {
            f32x4 va = load4(A, (size_t)(bm * 32 + arow) * K + k0 + acol, f);
            *(f32x4*)&Asf[arow][acol] = va;
        }
        for (int it = 0; it < 4; ++it) {
            int g = tid + it * 256;
            int krow = g >> 5, ng = (g & 31) * 4;
            f32x4 v = load4(B, (size_t)(k0 + krow) * N + bn * 128 + ng, f);
            Bsf[ng + 0][krow] = v[0];
            Bsf[ng + 1][krow] = v[1];
            Bsf[ng + 2][krow] = v[2];
            Bsf[ng + 3][krow] = v[3];
        }
        __syncthreads();
        bf16x8 ah[2], al[2], bh[2], bl[2];
        for (int mt = 0; mt < 2; ++mt) split8(&Asf[mt * 16 + l16][quad * 8], ah[mt], al[mt]);
        for (int nt = 0; nt < 2; ++nt) split8(&Bsf[wn + nt * 16 + l16][quad * 8], bh[nt], bl[nt]);
        for (int mt = 0; mt < 2; ++mt)
            for (int nt = 0; nt < 2; ++nt) {
                acc[mt][nt] = __builtin_amdgcn_mfma_f32_16x16x32_bf16(al[mt], bh[nt], acc[mt][nt], 0, 0, 0);
                acc[mt][nt] = __builtin_amdgcn_mfma_f32_16x16x32_bf16(ah[mt], bl[nt], acc[mt][nt], 0, 0, 0);
                acc[mt][nt] = __builtin_amdgcn_mfma_f32_16x16x32_bf16(ah[mt], bh[nt], acc[mt][nt], 0, 0, 0);
            }
        __syncthreads();
    }
    for (int mt = 0; mt < 2; ++mt)
        for (int nt = 0; nt < 2; ++nt)
#pragma unroll
            for (int r = 0; r < 4; ++r) {
                int col = bn * 128 + wn + nt * 16 + l16;
                int t = bm * 32 + mt * 16 + quad * 4 + r;
                float v = acc[mt][nt][r];
                float pv = __shfl_xor(v, 1);
                float o = v;
                if (t < 64) {
                    int j = (col & 63) >> 1;
                    float c, s;
                    cs_at(fc, fs, f, t, j, c, s);
                    o = (lane & 1) ? (pv * s + v * c) : (v * c - pv * s);
                }
                C[(size_t)t * N + col] = o;
            }
}

// K-split (512 blocks, pre-split B) + Qe-split (32 blocks). grid 544.
__global__ __launch_bounds__(256) void split_dual_rope_k(const void* __restrict__ x,
                                                         const __bf16* __restrict__ Wtk_h,
                                                         const __bf16* __restrict__ Wtk_l,
                                                         float* __restrict__ Kf,
                                                         const void* __restrict__ wq,
                                                         float* __restrict__ Qe,
                                                         __bf16* __restrict__ Kb,
                                                         const void* __restrict__ fc,
                                                         const void* __restrict__ fs,
                                                         const int* __restrict__ flag) {
    __shared__ __align__(16) char smem[41472];
    bool f = (*flag != 0);
    int bid = blockIdx.x;
    if (bid < 512) {
        gemm_ksplit_body(x, Wtk_h, Wtk_l, Kf, Kb, f, bid >> 2, bid & 3, fc, fs, smem);
    } else {
        int i = bid - 512;
        gemm_qesplit_body(x, wq, Qe, 2048, f, i >> 4, i & 15, fc, fs, smem);
    }
}

// =====================================================================
// bf16 NT GEMM body: C[M][N] = A[M][K=2048] @ Bt[N][K]^T, f32 acc.
// global_load_lds staging into linear [128][64] LDS, BK=64, 4 waves.
// Epilogues: MODE_V plain bf16, MODE_Q fused RoPE (bit-exact), MODE_O.
// =====================================================================
__device__ __forceinline__ void gemm_nt_body(const __bf16* __restrict__ A,
                                             const __bf16* __restrict__ Bt,
                                             void* __restrict__ C, int N,
                                             int bm, int bn, bool f, int mode,
                                             const void* __restrict__ fc,
                                             const void* __restrict__ fs,
                                             char* smem) {
    const int K = DIMM;
    __bf16* As = (__bf16*)smem;             // 128*64*2 = 16384 B
    __bf16* Bs = (__bf16*)(smem + 16384);   // 16384 B
    int tid = threadIdx.x, wave = tid >> 6, lane = tid & 63;
    int quad = lane >> 4, l16 = lane & 15;
    int wm = (wave >> 1) * 64, wn = (wave & 1) * 64;
    const f32x4 z4 = {0.f, 0.f, 0.f, 0.f};
    f32x4 acc[4][4];
    for (int a = 0; a < 4; ++a) for (int b = 0; b < 4; ++b) acc[a][b] = z4;
    const __bf16* Ab = A  + (size_t)(bm * 128) * K;
    const __bf16* Bb = Bt + (size_t)(bn * 128) * K;
    for (int k0 = 0; k0 < K; k0 += 64) {
#pragma unroll
        for (int it = 0; it < 4; ++it) {
            int ci = it * 256 + tid;
            int row = ci >> 3, c8 = (ci & 7) * 8;
            gl_lds16(Ab + (size_t)row * K + k0 + c8, As + ci * 8);
            gl_lds16(Bb + (size_t)row * K + k0 + c8, Bs + ci * 8);
        }
        __syncthreads();
#pragma unroll
        for (int ks = 0; ks < 2; ++ks) {
            bf16x8 af[4], bfr[4];
#pragma unroll
            for (int mt = 0; mt < 4; ++mt)
                af[mt]  = *(const bf16x8*)&As[(wm + mt * 16 + l16) * 64 + ks * 32 + quad * 8];
#pragma unroll
            for (int nt = 0; nt < 4; ++nt)
                bfr[nt] = *(const bf16x8*)&Bs[(wn + nt * 16 + l16) * 64 + ks * 32 + quad * 8];
#pragma unroll
            for (int mt = 0; mt < 4; ++mt)
#pragma unroll
                for (int nt = 0; nt < 4; ++nt)
                    acc[mt][nt] = __builtin_amdgcn_mfma_f32_16x16x32_bf16(af[mt], bfr[nt], acc[mt][nt], 0, 0, 0);
        }
        __syncthreads();
    }
    if (mode == MODE_Q) {
        for (int mt = 0; mt < 4; ++mt)
            for (int nt = 0; nt < 4; ++nt)
#pragma unroll
                for (int r = 0; r < 4; ++r) {
                    int col = bn * 128 + wn + nt * 16 + l16;
                    int t = bm * 128 + wm + mt * 16 + quad * 4 + r;
                    float qv = (float)(__bf16)acc[mt][nt][r];
                    float pv = __shfl_xor(qv, 1);
                    int j = (col & 63) >> 1;
                    float c, s;
                    cs_at(fc, fs, f, t, j, c, s);
                    float o = (lane & 1) ? (pv * s + qv * c) : (qv * c - pv * s);
                    ((__bf16*)C)[(size_t)t * N + col] = (__bf16)o;
                }
    } else if (mode == MODE_O) {
        bool f32o = f;
        for (int mt = 0; mt < 4; ++mt)
            for (int nt = 0; nt < 4; ++nt) {
                int rowb = bm * 128 + wm + mt * 16 + quad * 4;
                int col = bn * 128 + wn + nt * 16 + l16;
                if (f32o) {
                    for (int r = 0; r < 4; ++r)
                        ((float*)C)[(size_t)(rowb + r) * N + col] = acc[mt][nt][r];
                } else {
                    for (int r = 0; r < 4; ++r)
                        ((__bf16*)C)[(size_t)(rowb + r) * N + col] = (__bf16)acc[mt][nt][r];
                }
            }
    } else {
        for (int mt = 0; mt < 4; ++mt)
            for (int nt = 0; nt < 4; ++nt) {
                int rowb = bm * 128 + wm + mt * 16 + quad * 4;
                int col = bn * 128 + wn + nt * 16 + l16;
                for (int r = 0; r < 4; ++r)
                    ((__bf16*)C)[(size_t)(rowb + r) * N + col] = (__bf16)acc[mt][nt][r];
            }
    }
}

// Merged Q-proj (rope epilogue) + V-proj dispatch. grid (40,16).
__global__ __launch_bounds__(256) void gemm_qv_k(const __bf16* __restrict__ xbf,
                                                 const __bf16* __restrict__ Wtq,
                                                 const __bf16* __restrict__ Wtv,
                                                 __bf16* __restrict__ Qb,
                                                 __bf16* __restrict__ Vb,
                                                 const void* __restrict__ fc,
                                                 const void* __restrict__ fs,
                                                 const int* __restrict__ flag) {
    __shared__ __align__(16) char smem[32768];
    bool f = (*flag != 0);
    int bx = blockIdx.x, by = blockIdx.y;
    if (bx < 32) {
        gemm_nt_body(xbf, Wtq, Qb, 2048, bx, by, f, MODE_Q, fc, fs, smem);
    } else {
        int bm = (bx - 32) * 4 + (by >> 2), bn = by & 3;
        gemm_nt_body(xbf, Wtv, Vb, 512, bm, bn, f, MODE_V, nullptr, nullptr, smem);
    }
}

// Output projection: AO @ Wto (NT), f32 store if f32 inputs.
__global__ __launch_bounds__(256) void gemm_o_k(const __bf16* __restrict__ A,
                                                const __bf16* __restrict__ Bt,
                                                void* __restrict__ C,
                                                const int* __restrict__ flag) {
    __shared__ __align__(16) char smem[32768];
    bool f = (*flag != 0);
    gemm_nt_body(A, Bt, C, 2048, blockIdx.x, blockIdx.y, f, MODE_O, nullptr, nullptr, smem);
}

// =====================================================================
// Estimation partial row stats over a 512-key slice. grid (32 heads, 8).
// Also zeroes its head/slice of diag.
// =====================================================================
__global__ __launch_bounds__(256) void est_part_k(const float* __restrict__ Qe,
                                                  const float* __restrict__ Kf,
                                                  float* __restrict__ pm,
                                                  float* __restrict__ ps,
                                                  float* __restrict__ diag) {
    int h = blockIdx.x, sl = blockIdx.y;
    int tid = threadIdx.x, wave = tid >> 6, lane = tid & 63;
    int quad = lane >> 4, l16 = lane & 15;
    for (int i = tid; i < 512; i += 256) diag[h * SEQ + sl * 512 + i] = 0.f;
    __shared__ float Ml[64];
    __shared__ float pA[4][64];
    bf16x8 qh[4][2], ql[4][2];
    for (int mt = 0; mt < 4; ++mt)
        for (int kc = 0; kc < 2; ++kc)
            split8(Qe + (size_t)(mt * 16 + l16) * DIMM + h * HD + kc * 32 + quad * 8,
                   qh[mt][kc], ql[mt][kc]);
    int kvoff = (h >> 2) * HD;
    float pmax[4][4];
    for (int mt = 0; mt < 4; ++mt) for (int r = 0; r < 4; ++r) pmax[mt][r] = -3.0e38f;
    for (int jb = wave; jb < 8; jb += 4)
        for (int c = 0; c < 4; ++c) {
            int j0 = sl * 512 + jb * 64 + c * 16;
            const float* kp = Kf + (size_t)(j0 + l16) * (NKV * HD) + kvoff + quad * 8;
            bf16x8 kh0, kl0, kh1, kl1;
            split8(kp, kh0, kl0);
            split8(kp + 32, kh1, kl1);
            int j = j0 + l16;
            for (int mt = 0; mt < 4; ++mt) {
                f32x4 acc = {0.f, 0.f, 0.f, 0.f};
                acc = __builtin_amdgcn_mfma_f32_16x16x32_bf16(ql[mt][0], kh0, acc, 0, 0, 0);
                acc = __builtin_amdgcn_mfma_f32_16x16x32_bf16(qh[mt][0], kl0, acc, 0, 0, 0);
                acc = __builtin_amdgcn_mfma_f32_16x16x32_bf16(qh[mt][0], kh0, acc, 0, 0, 0);
                acc = __builtin_amdgcn_mfma_f32_16x16x32_bf16(ql[mt][1], kh1, acc, 0, 0, 0);
                acc = __builtin_amdgcn_mfma_f32_16x16x32_bf16(qh[mt][1], kl1, acc, 0, 0, 0);
                acc = __builtin_amdgcn_mfma_f32_16x16x32_bf16(qh[mt][1], kh1, acc, 0, 0, 0);
                for (int r = 0; r < 4; ++r) {
                    int q = mt * 16 + quad * 4 + r;
                    float sv = acc[r] * 0.125f;
                    if (j >= SEQ - 64 && q < j - (SEQ - 64)) sv = -1e30f;
                    pmax[mt][r] = fmaxf(pmax[mt][r], sv);
                }
            }
        }
    for (int mt = 0; mt < 4; ++mt)
        for (int r = 0; r < 4; ++r)
            for (int m2 = 1; m2 < 16; m2 <<= 1)
                pmax[mt][r] = fmaxf(pmax[mt][r], __shfl_xor(pmax[mt][r], m2));
    if (l16 == 0)
        for (int mt = 0; mt < 4; ++mt)
            for (int r = 0; r < 4; ++r)
                pA[wave][mt * 16 + quad * 4 + r] = pmax[mt][r];
    __syncthreads();
    if (tid < 64)
        Ml[tid] = fmaxf(fmaxf(pA[0][tid], pA[1][tid]), fmaxf(pA[2][tid], pA[3][tid]));
    __syncthreads();
    float mreg[4][4];
    for (int mt = 0; mt < 4; ++mt)
        for (int r = 0; r < 4; ++r)
            mreg[mt][r] = Ml[mt * 16 + quad * 4 + r];
    float psum[4][4];
    for (int mt = 0; mt < 4; ++mt) for (int r = 0; r < 4; ++r) psum[mt][r] = 0.f;
    for (int jb = wave; jb < 8; jb += 4)
        for (int c = 0; c < 4; ++c) {
            int j0 = sl * 512 + jb * 64 + c * 16;
            const float* kp = Kf + (size_t)(j0 + l16) * (NKV * HD) + kvoff + quad * 8;
            bf16x8 kh0, kl0, kh1, kl1;
            split8(kp, kh0, kl0);
            split8(kp + 32, kh1, kl1);
            int j = j0 + l16;
            for (int mt = 0; mt < 4; ++mt) {
                f32x4 acc = {0.f, 0.f, 0.f, 0.f};
                acc = __builtin_amdgcn_mfma_f32_16x16x32_bf16(ql[mt][0], kh0, acc, 0, 0, 0);
                acc = __builtin_amdgcn_mfma_f32_16x16x32_bf16(qh[mt][0], kl0, acc, 0, 0, 0);
                acc = __builtin_amdgcn_mfma_f32_16x16x32_bf16(qh[mt][0], kh0, acc, 0, 0, 0);
                acc = __builtin_amdgcn_mfma_f32_16x16x32_bf16(ql[mt][1], kh1, acc, 0, 0, 0);
                acc = __builtin_amdgcn_mfma_f32_16x16x32_bf16(qh[mt][1], kl1, acc, 0, 0, 0);
                acc = __builtin_amdgcn_mfma_f32_16x16x32_bf16(qh[mt][1], kh1, acc, 0, 0, 0);
                for (int r = 0; r < 4; ++r) {
                    int q = mt * 16 + quad * 4 + r;
                    float sv = acc[r] * 0.125f;
                    if (j >= SEQ - 64 && q < j - (SEQ - 64)) sv = -1e30f;
                    psum[mt][r] += __expf(sv - mreg[mt][r]);
                }
            }
        }
    for (int mt = 0; mt < 4; ++mt)
        for (int r = 0; r < 4; ++r)
            for (int m2 = 1; m2 < 16; m2 <<= 1)
                psum[mt][r] += __shfl_xor(psum[mt][r], m2);
    if (l16 == 0)
        for (int mt = 0; mt < 4; ++mt)
            for (int r = 0; r < 4; ++r)
                pA[wave][mt * 16 + quad * 4 + r] = psum[mt][r];
    __syncthreads();
    if (tid < 64) {
        pm[(h * 8 + sl) * 64 + tid] = Ml[tid];
        ps[(h * 8 + sl) * 64 + tid] = pA[0][tid] + pA[1][tid] + pA[2][tid] + pA[3][tid];
    }
}

// =====================================================================
// vertical/diag accumulation. grid (32 heads, 32 key-chunks of 128).
// rmax/rsum computed INLINE from pm/ps.
// =====================================================================
__global__ __launch_bounds__(256) void vert_diag_k(const float* __restrict__ Qe,
                                                   const float* __restrict__ Kf,
                                                   const float* __restrict__ pm,
                                                   const float* __restrict__ ps,
                                                   float* __restrict__ vert,
                                                   float* __restrict__ diag) {
    int h = blockIdx.x, jb = blockIdx.y;
    int tid = threadIdx.x, wave = tid >> 6, lane = tid & 63;
    int quad = lane >> 4, l16 = lane & 15;
    __shared__ float P[64][132];
    __shared__ float dloc[192];
    __shared__ float rm_l[64], rs_l[64];
    for (int i = tid; i < 192; i += 256) dloc[i] = 0.f;
    if (tid < 64) {
        float M = -3.0e38f;
        for (int sl = 0; sl < 8; ++sl) M = fmaxf(M, pm[(h * 8 + sl) * 64 + tid]);
        float S = 0.f;
        for (int sl = 0; sl < 8; ++sl)
            S += ps[(h * 8 + sl) * 64 + tid] * __expf(pm[(h * 8 + sl) * 64 + tid] - M);
        rm_l[tid] = M;
        rs_l[tid] = S;
    }
    bf16x8 qh[4][2], ql[4][2];
    for (int mt = 0; mt < 4; ++mt)
        for (int kc = 0; kc < 2; ++kc)
            split8(Qe + (size_t)(mt * 16 + l16) * DIMM + h * HD + kc * 32 + quad * 8,
                   qh[mt][kc], ql[mt][kc]);
    __syncthreads();
    float rm[4][4], rs[4][4];
    for (int mt = 0; mt < 4; ++mt)
        for (int r = 0; r < 4; ++r) {
            int q = mt * 16 + quad * 4 + r;
            rm[mt][r] = rm_l[q];
            rs[mt][r] = rs_l[q];
        }
    int kvoff = (h >> 2) * HD;
    for (int c = 0; c < 2; ++c) {
        int jl0 = wave * 32 + c * 16;
        int j0 = jb * 128 + jl0;
        const float* kp = Kf + (size_t)(j0 + l16) * (NKV * HD) + kvoff + quad * 8;
        bf16x8 kh0, kl0, kh1, kl1;
        split8(kp, kh0, kl0);
        split8(kp + 32, kh1, kl1);
        int j = j0 + l16;
        for (int mt = 0; mt < 4; ++mt) {
            f32x4 acc = {0.f, 0.f, 0.f, 0.f};
            acc = __builtin_amdgcn_mfma_f32_16x16x32_bf16(ql[mt][0], kh0, acc, 0, 0, 0);
            acc = __builtin_amdgcn_mfma_f32_16x16x32_bf16(qh[mt][0], kl0, acc, 0, 0, 0);
            acc = __builtin_amdgcn_mfma_f32_16x16x32_bf16(qh[mt][0], kh0, acc, 0, 0, 0);
            acc = __builtin_amdgcn_mfma_f32_16x16x32_bf16(ql[mt][1], kh1, acc, 0, 0, 0);
            acc = __builtin_amdgcn_mfma_f32_16x16x32_bf16(qh[mt][1], kl1, acc, 0, 0, 0);
            acc = __builtin_amdgcn_mfma_f32_16x16x32_bf16(qh[mt][1], kh1, acc, 0, 0, 0);
            for (int r = 0; r < 4; ++r) {
                int q = mt * 16 + quad * 4 + r;
                float sv = acc[r] * 0.125f;
                if (j >= SEQ - 64 && q < j - (SEQ - 64)) sv = -1e30f;
                P[q][jl0 + l16] = __expf(sv - rm[mt][r]) / rs[mt][r];
            }
        }
    }
    __syncthreads();
    if (tid < 128) {
        float vacc = 0.f;
        for (int q = 0; q < 64; ++q) {
            float pb = P[q][tid];
            vacc += pb;
            if (jb * 128 + tid + 63 - q < SEQ) atomicAdd(&dloc[tid + 63 - q], pb);
        }
        vert[h * SEQ + jb * 128 + tid] = vacc;
    }
    __syncthreads();
    for (int i = tid; i < 192; i += 256) {
        int g = jb * 128 + i;
        if (g < SEQ) atomicAdd(&diag[h * SEQ + g], dloc[i]);
    }
}

// =====================================================================
// Merged: per-head top-k (32 blocks) + wq/wv transpose (5120 blocks).
// Transpose outputs (Wtq/Wtv) disjoint from topk inputs -> safe.
// =====================================================================
__global__ __launch_bounds__(256) void topk_qvt_k(const float* __restrict__ vert,
                                                  const float* __restrict__ diag,
                                                  int* __restrict__ skeys,
                                                  const void* __restrict__ wq,
                                                  __bf16* __restrict__ Wtq,
                                                  const void* __restrict__ wv,
                                                  __bf16* __restrict__ Wtv,
                                                  const int* __restrict__ flag) {
    if (blockIdx.x >= 32) {
        bool f = (*flag != 0);
        int id = blockIdx.x - 32;
        int bx = id >> 6, by = id & 63;
        if (bx < 64) transpose_body(wq, Wtq, 2048, 2048, f, bx * 32, by * 32);
        else         transpose_body(wv, Wtv, 2048,  512, f, (bx - 64) * 32, by * 32);
        return;
    }
    __shared__ int cnt[4096];
    __shared__ int hist4[4][256];
    __shared__ int scanb[256];
    __shared__ int B_sh, kk_sh;
    int h = blockIdx.x, tid = threadIdx.x, wave = tid >> 6;
    for (int i = tid; i < 4096; i += 256) cnt[i] = 0;
    __syncthreads();
    for (int selp = 0; selp < 2; ++selp) {
        const float* vals = (selp == 0 ? vert : diag) + h * SEQ;
        int k = (selp == 0) ? 300 : 800;
        bool flip = (selp == 1);
        unsigned bits[16];
        for (int g = 0; g < 4; ++g) {
            f32x4 v = *(const f32x4*)(vals + tid * 16 + g * 4);
            for (int e = 0; e < 4; ++e) bits[g * 4 + e] = __float_as_uint(v[e]);
        }
        unsigned prefix = 0;
        int kk = k;
        for (int pass = 0; pass < 4; ++pass) {
            int sh = 8 * (3 - pass);
            for (int w = 0; w < 4; ++w) hist4[w][tid] = 0;
            __syncthreads();
            for (int e = 0; e < 16; ++e) {
                unsigned b = bits[e];
                bool in = (pass == 0) || ((b >> (sh + 8)) == prefix);
                if (in) atomicAdd(&hist4[wave][(b >> sh) & 255], 1);
            }
            __syncthreads();
            scanb[tid] = hist4[0][tid] + hist4[1][tid] + hist4[2][tid] + hist4[3][tid];
            __syncthreads();
            for (int off = 1; off < 256; off <<= 1) {
                int v = (tid + off < 256) ? scanb[tid + off] : 0;
                __syncthreads();
                scanb[tid] += v;
                __syncthreads();
            }
            int sufNext = (tid < 255) ? scanb[tid + 1] : 0;
            if (scanb[tid] >= kk && sufNext < kk) { B_sh = tid; kk_sh = kk - sufNext; }
            __syncthreads();
            prefix = (prefix << 8) | (unsigned)B_sh;
            kk = kk_sh;
            __syncthreads();
        }
        int localEq = 0;
        for (int e = 0; e < 16; ++e) {
            unsigned b = bits[e];
            if (b > prefix) {
                int idx = tid * 16 + e;
                atomicAdd(&cnt[flip ? (4095 - idx) : idx], 1);
            } else if (b == prefix) ++localEq;
        }
        scanb[tid] = localEq;
        __syncthreads();
        for (int off = 1; off < 256; off <<= 1) {
            int v = (tid >= off) ? scanb[tid - off] : 0;
            __syncthreads();
            scanb[tid] += v;
            __syncthreads();
        }
        int eqOff = scanb[tid] - localEq;
        int taken = 0;
        for (int e = 0; e < 16; ++e) {
            unsigned b = bits[e];
            if (b == prefix) {
                if (eqOff + taken < kk) {
                    int idx = tid * 16 + e;
                    atomicAdd(&cnt[flip ? (4095 - idx) : idx], 1);
                }
                ++taken;
            }
        }
        __syncthreads();
    }
    int base = tid * 16;
    int loc[16];
    int s = 0;
    for (int e = 0; e < 16; ++e) { loc[e] = s; s += cnt[base + e]; }
    scanb[tid] = s;
    __syncthreads();
    for (int off = 1; off < 256; off <<= 1) {
        int v = (tid >= off) ? scanb[tid - off] : 0;
        __syncthreads();
        scanb[tid] += v;
        __syncthreads();
    }
    int chunkExcl = scanb[tid] - s;
    int* out = skeys + h * NSPP;
    for (int e = 0; e < 16; ++e) {
        int c = cnt[base + e];
        int pos = chunkExcl + loc[e];
        for (int r = 0; r < c; ++r) out[pos + r] = base + e;
    }
    for (int i = NSP + tid; i < NSPP; i += 256) out[i] = 0x7fffffff;
}

// =====================================================================
// Merged: gather sparse K/V (576 blocks) + wo transpose (4096 blocks).
// =====================================================================
__global__ __launch_bounds__(256) void gather_wot_k(const __bf16* __restrict__ Kb,
                                                    const __bf16* __restrict__ Vb,
                                                    const int* __restrict__ skeys,
                                                    __bf16* __restrict__ Ksp,
                                                    __bf16* __restrict__ VspT,
                                                    const void* __restrict__ wo,
                                                    __bf16* __restrict__ Wto,
                                                    const int* __restrict__ flag) {
    int bid = blockIdx.x;
    if (bid >= 576) {
        bool f = (*flag != 0);
        int id = bid - 576;
        transpose_body(wo, Wto, 2048, 2048, f, (id >> 6) * 32, (id & 63) * 32);
        return;
    }
    int h = bid / 18, jb = bid % 18;
    __shared__ __bf16 tile[64][72];
    int tid = threadIdx.x;
    int jl = tid >> 2, d0 = (tid & 3) * 16;
    int j = jb * 64 + jl;
    int key = skeys[h * NSPP + j];
    int kv = (h >> 2) * HD;
    const bf16x8 z = {};
    bf16x8 k0v = z, k1v = z, v0v = z, v1v = z;
    if ((unsigned)key < SEQ) {
        const __bf16* ks = Kb + (size_t)key * (NKV * HD) + kv + d0;
        const __bf16* vs = Vb + (size_t)key * (NKV * HD) + kv + d0;
        k0v = *(const bf16x8*)ks; k1v = *(const bf16x8*)(ks + 8);
        v0v = *(const bf16x8*)vs; v1v = *(const bf16x8*)(vs + 8);
    }
    __bf16* kd = Ksp + ((size_t)h * NSPP + j) * HD + d0;
    *(bf16x8*)kd = k0v;
    *(bf16x8*)(kd + 8) = k1v;
    *(bf16x8*)&tile[jl][d0] = v0v;
    *(bf16x8*)&tile[jl][d0 + 8] = v1v;
    __syncthreads();
    int d = tid >> 2, jl0 = (tid & 3) * 16;
    bf16x8 o0, o1;
    for (int e = 0; e < 8; ++e) { o0[e] = tile[jl0 + e][d]; o1[e] = tile[jl0 + 8 + e][d]; }
    __bf16* vt = VspT + ((size_t)h * HD + d) * NSPP + jb * 64 + jl0;
    *(bf16x8*)vt = o0;
    *(bf16x8*)(vt + 8) = o1;
}

// =====================================================================
// Sparse attention: grid (64 q-tiles of 64, 32 heads). 8 waves (512 thr).
// 3-phase LDS-score structure, QBLK=64. AO aliases Qb in-place
// (block-local RAW only; validated round 10).
// =====================================================================
__global__ __launch_bounds__(512) void sparse_attn_k(const __bf16* Qb,
                                                     const __bf16* __restrict__ Ksp,
                                                     const __bf16* __restrict__ VspT,
                                                     const int* __restrict__ skeys,
                                                     __bf16* AO) {
    int qb = blockIdx.x, h = blockIdx.y;
    int tid = threadIdx.x, wave = tid >> 6, lane = tid & 63;
    int quad = lane >> 4, l16 = lane & 15;
    __shared__ __bf16 sc[64][1160];
    __shared__ float rsm[64];
    int t0 = qb * 64;
    bf16x8 aq[4][2];
#pragma unroll
    for (int qs = 0; qs < 4; ++qs)
#pragma unroll
        for (int kc = 0; kc < 2; ++kc)
            aq[qs][kc] = *(const bf16x8*)(Qb + (size_t)(t0 + qs * 16 + l16) * DIMM + h * HD + kc * 32 + quad * 8);
    const __bf16* Kh = Ksp + (size_t)h * NSPP * HD;
    const int* sk = skeys + h * NSPP;
#pragma unroll
    for (int c = 0; c < 9; ++c) {
        int j0 = wave * 144 + c * 16;
        const __bf16* kp = Kh + (size_t)(j0 + l16) * HD + quad * 8;
        bf16x8 b0 = *(const bf16x8*)kp;
        bf16x8 b1 = *(const bf16x8*)(kp + 32);
        int j = j0 + l16;
        int key = sk[j];
#pragma unroll
        for (int qs = 0; qs < 4; ++qs) {
            f32x4 acc = {0.f, 0.f, 0.f, 0.f};
            acc = __builtin_amdgcn_mfma_f32_16x16x32_bf16(aq[qs][0], b0, acc, 0, 0, 0);
            acc = __builtin_amdgcn_mfma_f32_16x16x32_bf16(aq[qs][1], b1, acc, 0, 0, 0);
            int qg = t0 + qs * 16 + quad * 4;
#pragma unroll
            for (int r = 0; r < 4; ++r) {
                float sv = acc[r] * 0.125f;
                if (key > qg + r) sv = -1e30f;
                sc[qs * 16 + quad * 4 + r][j] = (__bf16)sv;
            }
        }
    }
    __syncthreads();
    {
        int row = tid >> 3, sub = tid & 7;
        int c0 = sub * 144;
        float mx = -3.0e38f;
        for (int i = 0; i < 18; ++i) {
            bf16x8 v = *(const bf16x8*)&sc[row][c0 + i * 8];
            for (int e = 0; e < 8; ++e) mx = fmaxf(mx, (float)v[e]);
        }
        for (int m2 = 1; m2 < 8; m2 <<= 1) mx = fmaxf(mx, __shfl_xor(mx, m2, 8));
        float sm = 0.f;
        for (int i = 0; i < 18; ++i) {
            int cb = c0 + i * 8;
            bf16x8 v = *(const bf16x8*)&sc[row][cb];
            bf16x8 pw;
            for (int e = 0; e < 8; ++e) {
                float pv = 0.f;
                if (cb + e < NSP) { pv = __expf((float)v[e] - mx); sm += pv; }
                pw[e] = (__bf16)pv;
            }
            *(bf16x8*)&sc[row][cb] = pw;
        }
        for (int m2 = 1; m2 < 8; m2 <<= 1) sm += __shfl_xor(sm, m2, 8);
        if (sub == 0) rsm[row] = sm;
    }
    __syncthreads();
    int qs = wave >> 1, dh = wave & 1;
    const f32x4 z4 = {0.f, 0.f, 0.f, 0.f};
    f32x4 o0 = z4, o1 = z4;
    const __bf16* Vh = VspT + ((size_t)h * HD + dh * 32) * NSPP;
#pragma unroll 4
    for (int c = 0; c < 36; ++c) {
        int kb = c * 32;
        bf16x8 pa = *(const bf16x8*)&sc[qs * 16 + l16][kb + quad * 8];
        bf16x8 v0 = *(const bf16x8*)(Vh + (size_t)l16 * NSPP + kb + quad * 8);
        bf16x8 v1 = *(const bf16x8*)(Vh + (size_t)(16 + l16) * NSPP + kb + quad * 8);
        o0 = __builtin_amdgcn_mfma_f32_16x16x32_bf16(pa, v0, o0, 0, 0, 0);
        o1 = __builtin_amdgcn_mfma_f32_16x16x32_bf16(pa, v1, o1, 0, 0, 0);
    }
#pragma unroll
    for (int r = 0; r < 4; ++r) {
        int ql = qs * 16 + quad * 4 + r;
        float inv = 1.f / rsm[ql];
        size_t base = (size_t)(t0 + ql) * DIMM + h * HD + dh * 32;
        AO[base + l16]      = (__bf16)(o0[r] * inv);
        AO[base + 16 + l16] = (__bf16)(o1[r] * inv);
    }
}

// =====================================================================
// Launch. 10 dispatches, selection-first order. Workspace liveness
// (step numbers = dispatch order; co-resident writes never alias reads):
//  1 detect  2 convert+wkT  3 split_dual  4 est  5 vert  6 topk+qvT
//  7 gemm_qv  8 gather+woT  9 attn  10 gemm_o
//   Wtk_h  0..2097152        [2 -> 3]   (Qb region, Qb written at 7)
//   Wtk_l  2097152..4194304  [2 -> 3]
//   Kf32   4194304..12582912 [3 -> 5]
//   Qef32  12582912..13631488[3 -> 5]   (64 rows only)
//   pm     13631488..13697024[4 -> 5]
//   ps     13697024..13762560[4 -> 5]
//   vert   13762560..14286848[5 -> 6]
//   diag   14286848..14811136[4 -> 6]
//   Qb     0..16777216       [7 -> 10]  (attn rewrites in-place)
//   Kb     16777216..20971520[3 -> 8]
//   Vb     20971520..25165824[7 -> 8]
//   xbf    25165824..41943040[2 -> 7]
//   Ksp    25165824..29884416[8 -> 9]   (xbf dead)
//   VspT   29884416..34603008[8 -> 9]
//   Wtq    41943040..50331648[6 -> 7]
//   Wto    41943040..50331648[8 -> 10]  (Wtq dead)
//   Wtv    50331648..52428800[6 -> 7]
//   skeys  52445184..52592640[6 -> 9]
//   flag   52592640           [1 -> ]
// =====================================================================
extern "C" void kernel_launch(void* const* d_in, const int* in_sizes, int n_in,
                              void* d_out, int out_size, void* d_ws, size_t ws_size,
                              hipStream_t stream) {
    const void* x  = d_in[0];
    const void* fc = d_in[1];
    const void* fs = d_in[2];
    const void* wq = d_in[3];
    const void* wk = d_in[4];
    const void* wv = d_in[5];
    const void* wo = d_in[6];
    char* ws = (char*)d_ws;

    __bf16* Wtk_h= (__bf16*)(ws + 0);
    __bf16* Wtk_l= (__bf16*)(ws + 2097152);
    float*  Kf32 = (float*)(ws + 4194304);
    float*  Qef32= (float*)(ws + 12582912);
    float*  pm   = (float*)(ws + 13631488);
    float*  ps   = (float*)(ws + 13697024);
    float*  vert = (float*)(ws + 13762560);
    float*  diag = (float*)(ws + 14286848);
    __bf16* Qb   = (__bf16*)(ws + 0);          // from step 7; also AO
    __bf16* Kb   = (__bf16*)(ws + 16777216);
    __bf16* Vb   = (__bf16*)(ws + 20971520);
    __bf16* xbf  = (__bf16*)(ws + 25165824);
    __bf16* Ksp  = (__bf16*)(ws + 25165824);   // after xbf dead
    __bf16* VspT = (__bf16*)(ws + 29884416);
    __bf16* Wtq  = (__bf16*)(ws + 41943040);
    __bf16* Wto  = (__bf16*)(ws + 41943040);   // after Wtq dead
    __bf16* Wtv  = (__bf16*)(ws + 50331648);
    int*    skeys= (int*)(ws + 52445184);
    int*    flag = (int*)(ws + 52592640);

    dim3 b256(256);
    detect_k<<<1, b256, 0, stream>>>(x, flag);
    // x -> xbf  +  wk -> Wtk_h/Wtk_l (transposed hi/lo split)
    convert_wkt_k<<<5120, b256, 0, stream>>>(x, xbf, wk, Wtk_h, Wtk_l, flag);
    // selection-path projections: K (pre-split B) + Qe (rows 0..63)
    split_dual_rope_k<<<544, b256, 0, stream>>>(x, Wtk_h, Wtk_l, Kf32, wq, Qef32,
                                                Kb, fc, fs, flag);
    est_part_k<<<dim3(32, 8), b256, 0, stream>>>(Qef32, Kf32, pm, ps, diag);
    vert_diag_k<<<dim3(32, 32), b256, 0, stream>>>(Qef32, Kf32, pm, ps, vert, diag);
    // topk + wq/wv transposes ride along
    topk_qvt_k<<<5152, b256, 0, stream>>>(vert, diag, skeys, wq, Wtq, wv, Wtv, flag);
    // value-path projections (Q rope fused, V)
    gemm_qv_k<<<dim3(40, 16), b256, 0, stream>>>(xbf, Wtq, Wtv, Qb, Vb, fc, fs, flag);
    // gather sparse K/V + wo transpose rides along
    gather_wot_k<<<4672, b256, 0, stream>>>(Kb, Vb, skeys, Ksp, VspT, wo, Wto, flag);
    // sparse attention (in-place Qb -> AO)
    sparse_attn_k<<<dim3(64, 32), dim3(512), 0, stream>>>(Qb, Ksp, VspT, skeys, Qb);
    // output projection
    gemm_o_k<<<dim3(32, 16), b256, 0, stream>>>(Qb, Wto, d_out, flag);
}

// Round 12
// 776.198 us; speedup vs baseline: 1.1705x; 1.1705x over previous
//
#include <hip/hip_runtime.h>
#include <hip/hip_bf16.h>
#include <math.h>
#include <stdint.h>

// ---- problem constants ----
#define SEQ   4096
#define DIMM  2048
#define NH    32
#define NKV   8
#define HD    64
#define NSP   1100   // 300 vertical + 800 slash (duplicates kept)
#define NSPP  1152   // padded to multiple of 64

typedef __bf16 bf16x8 __attribute__((ext_vector_type(8)));
typedef float  f32x4  __attribute__((ext_vector_type(4)));

#define MODE_V 0
#define MODE_Q 1
#define MODE_O 2

// Split a run of 8 f32 into hi/lo bf16 fragments (hi+lo ~ f32 fidelity).
__device__ inline void split8(const float* __restrict__ p, bf16x8& h, bf16x8& l) {
#pragma unroll
    for (int i = 0; i < 8; ++i) {
        float v = p[i];
        __bf16 hv = (__bf16)v;
        h[i] = hv;
        l[i] = (__bf16)(v - (float)hv);
    }
}
// Load 4 consecutive elements as f32 from f32-or-bf16 memory.
__device__ inline f32x4 load4(const void* __restrict__ p, size_t idx, bool f) {
    if (f) return *(const f32x4*)((const float*)p + idx);
    const __bf16* b = (const __bf16*)p + idx;
    f32x4 v;
    v[0] = (float)b[0]; v[1] = (float)b[1]; v[2] = (float)b[2]; v[3] = (float)b[3];
    return v;
}
// Async global->LDS 16B copy (gfx950). LDS dest = wave-uniform base + lane*16.
__device__ __forceinline__ void gl_lds16(const __bf16* __restrict__ g, __bf16* l) {
    __builtin_amdgcn_global_load_lds(
        (const __attribute__((address_space(1))) void*)g,
        (__attribute__((address_space(3))) void*)l, 16, 0, 0);
}
// cos/sin fetch (f32-or-bf16 table)
__device__ __forceinline__ void cs_at(const void* fc, const void* fs, bool f,
                                      int t, int j, float& c, float& s) {
    if (f) {
        c = ((const float*)fc)[t * 32 + j];
        s = ((const float*)fs)[t * 32 + j];
    } else {
        c = (float)((const __bf16*)fc)[t * 32 + j];
        s = (float)((const __bf16*)fs)[t * 32 + j];
    }
}

// =====================================================================
// Input-dtype detection: flag=1 -> f32 inputs/outputs, flag=0 -> bf16.
// =====================================================================
__global__ __launch_bounds__(256) void detect_k(const void* __restrict__ x,
                                                int* __restrict__ flag) {
    const __bf16* p = (const __bf16*)x;
    int tid = threadIdx.x;
    bool bad = false;
    for (int i = 0; i < 16; ++i) {
        float v = fabsf((float)p[tid * 16 + i]);
        if (!(v <= 1e10f)) bad = true;    // catches huge AND NaN
    }
    unsigned long long m = __ballot(bad);
    __shared__ unsigned long long w[4];
    if ((tid & 63) == 0) w[tid >> 6] = m;
    __syncthreads();
    if (tid == 0) flag[0] = ((w[0] | w[1] | w[2] | w[3]) != 0ULL) ? 1 : 0;
}

// =====================================================================
// Tile transpose + convert body: out[c][r] = (bf16)in[r][c]
// =====================================================================
__device__ __forceinline__ void transpose_body(const void* __restrict__ in,
                                               __bf16* __restrict__ out,
                                               int R, int C, bool f,
                                               int cb, int rb) {
    __shared__ __bf16 tile[32][33];
    int tx = threadIdx.x & 31, ty = threadIdx.x >> 5;   // 32 x 8
    for (int i = 0; i < 32; i += 8) {
        size_t idx = (size_t)(rb + ty + i) * C + cb + tx;
        float v = f ? ((const float*)in)[idx] : (float)((const __bf16*)in)[idx];
        tile[ty + i][tx] = (__bf16)v;
    }
    __syncthreads();
    for (int i = 0; i < 32; i += 8)
        out[(size_t)(cb + ty + i) * R + rb + tx] = tile[tx][ty + i];
}

// Transpose with hi/lo split: oh/ol[c][r] = split(f32 in[r][c]).
__device__ __forceinline__ void transpose_split_body(const void* __restrict__ in,
                                                     __bf16* __restrict__ oh,
                                                     __bf16* __restrict__ ol,
                                                     int R, int C, bool f,
                                                     int cb, int rb) {
    __shared__ float tf[32][33];
    int tx = threadIdx.x & 31, ty = threadIdx.x >> 5;   // 32 x 8
    for (int i = 0; i < 32; i += 8) {
        size_t idx = (size_t)(rb + ty + i) * C + cb + tx;
        tf[ty + i][tx] = f ? ((const float*)in)[idx] : (float)((const __bf16*)in)[idx];
    }
    __syncthreads();
    for (int i = 0; i < 32; i += 8) {
        float v = tf[tx][ty + i];
        __bf16 h = (__bf16)v;
        size_t o = (size_t)(cb + ty + i) * R + rb + tx;
        oh[o] = h;
        ol[o] = (__bf16)(v - (float)h);
    }
}

// =====================================================================
// Merged convert + ALL weight transposes. grid 10240:
//  [0,4096)      x -> xbf
//  [4096,5120)   wk -> Wtk_h/Wtk_l (transposed hi/lo split)
//  [5120,9216)   wq -> Wtq
//  [9216,10240)  wv -> Wtv
// =====================================================================
__global__ __launch_bounds__(256) void convert_all_k(const void* __restrict__ x,
                                                     __bf16* __restrict__ xb,
                                                     const void* __restrict__ wk,
                                                     __bf16* __restrict__ Wtk_h,
                                                     __bf16* __restrict__ Wtk_l,
                                                     const void* __restrict__ wq,
                                                     __bf16* __restrict__ Wtq,
                                                     const void* __restrict__ wv,
                                                     __bf16* __restrict__ Wtv,
                                                     const int* __restrict__ flag) {
    int bid = blockIdx.x;
    bool f = (*flag != 0);
    if (bid < 4096) {
        int i0 = (bid * 256 + threadIdx.x) * 8;
        if (f) {
            const float* xf = (const float*)x;
            bf16x8 o;
            for (int i = 0; i < 8; ++i) o[i] = (__bf16)xf[i0 + i];
            *(bf16x8*)(xb + i0) = o;
        } else {
            *(bf16x8*)(xb + i0) = *(const bf16x8*)((const __bf16*)x + i0);
        }
    } else if (bid < 5120) {
        int id = bid - 4096;
        transpose_split_body(wk, Wtk_h, Wtk_l, 2048, 512, f, (id >> 6) * 32, (id & 63) * 32);
    } else if (bid < 9216) {
        int id = bid - 5120;
        transpose_body(wq, Wtq, 2048, 2048, f, (id >> 6) * 32, (id & 63) * 32);
    } else {
        int id = bid - 9216;
        transpose_body(wv, Wtv, 2048, 512, f, (id >> 6) * 32, (id & 63) * 32);
    }
}

// =====================================================================
// K-proj split GEMM: 32x128 tile, BK=64, PRE-SPLIT B (Wtk_h/l, NT bf16)
// via global_load_lds; A f32-LDS (stride 68) + split8 on A only.
// MFMA chain bit-exact (al*bh, ah*bl, ah*bh, old k-order).
// Epilogue: rope all rows; emit Kh=bf16(o), Kl=bf16(o-Kh) — the exact
// fragments est/vert previously computed via split8(Kf32). Kh == old Kb.
// =====================================================================
__device__ __forceinline__ void gemm_ksplit_body(const void* __restrict__ x,
                                                 const __bf16* __restrict__ Bh,
                                                 const __bf16* __restrict__ Bl,
                                                 __bf16* __restrict__ Kh,
                                                 __bf16* __restrict__ Kl,
                                                 bool f, int bm, int bn,
                                                 const void* __restrict__ fc,
                                                 const void* __restrict__ fs,
                                                 char* smem) {
    const int K = DIMM, N = 512;
    float (*Asf)[68] = (float (*)[68])smem;            // 32*68*4 = 8704 B
    __bf16* Bsh = (__bf16*)(smem + 8704);              // 16384 B
    __bf16* Bsl = (__bf16*)(smem + 8704 + 16384);      // 16384 B (tot 41472)
    int tid = threadIdx.x, wave = tid >> 6, lane = tid & 63;
    int quad = lane >> 4, l16 = lane & 15;
    int wn = wave * 32;
    const f32x4 z4 = {0.f, 0.f, 0.f, 0.f};
    f32x4 acc[2][2];
    for (int a = 0; a < 2; ++a) for (int b = 0; b < 2; ++b) acc[a][b] = z4;
    int arow = tid >> 3, ac8 = (tid & 7) * 8;
    const __bf16* Bhb = Bh + (size_t)(bn * 128) * K;
    const __bf16* Blb = Bl + (size_t)(bn * 128) * K;
    for (int k0 = 0; k0 < K; k0 += 64) {
        f32x4 va0 = load4(x, (size_t)(bm * 32 + arow) * K + k0 + ac8, f);
        f32x4 va1 = load4(x, (size_t)(bm * 32 + arow) * K + k0 + ac8 + 4, f);
        *(f32x4*)&Asf[arow][ac8]     = va0;
        *(f32x4*)&Asf[arow][ac8 + 4] = va1;
#pragma unroll
        for (int it = 0; it < 4; ++it) {
            int ci = it * 256 + tid;
            int row = ci >> 3, c8 = (ci & 7) * 8;
            gl_lds16(Bhb + (size_t)row * K + k0 + c8, Bsh + ci * 8);
            gl_lds16(Blb + (size_t)row * K + k0 + c8, Bsl + ci * 8);
        }
        __syncthreads();
#pragma unroll
        for (int ks = 0; ks < 2; ++ks) {
            bf16x8 ah[2], al[2], bh[2], bl[2];
#pragma unroll
            for (int mt = 0; mt < 2; ++mt)
                split8(&Asf[mt * 16 + l16][ks * 32 + quad * 8], ah[mt], al[mt]);
#pragma unroll
            for (int nt = 0; nt < 2; ++nt) {
                bh[nt] = *(const bf16x8*)&Bsh[(wn + nt * 16 + l16) * 64 + ks * 32 + quad * 8];
                bl[nt] = *(const bf16x8*)&Bsl[(wn + nt * 16 + l16) * 64 + ks * 32 + quad * 8];
            }
#pragma unroll
            for (int mt = 0; mt < 2; ++mt)
#pragma unroll
                for (int nt = 0; nt < 2; ++nt) {
                    acc[mt][nt] = __builtin_amdgcn_mfma_f32_16x16x32_bf16(al[mt], bh[nt], acc[mt][nt], 0, 0, 0);
                    acc[mt][nt] = __builtin_amdgcn_mfma_f32_16x16x32_bf16(ah[mt], bl[nt], acc[mt][nt], 0, 0, 0);
                    acc[mt][nt] = __builtin_amdgcn_mfma_f32_16x16x32_bf16(ah[mt], bh[nt], acc[mt][nt], 0, 0, 0);
                }
        }
        __syncthreads();
    }
    for (int mt = 0; mt < 2; ++mt)
        for (int nt = 0; nt < 2; ++nt)
#pragma unroll
            for (int r = 0; r < 4; ++r) {
                int col = bn * 128 + wn + nt * 16 + l16;
                int t = bm * 32 + mt * 16 + quad * 4 + r;
                float v = acc[mt][nt][r];
                float pv = __shfl_xor(v, 1);
                int j = (col & 63) >> 1;
                float c, s;
                cs_at(fc, fs, f, t, j, c, s);
                float o = (lane & 1) ? (pv * s + v * c) : (v * c - pv * s);
                __bf16 h16 = (__bf16)o;
                Kh[(size_t)t * N + col] = h16;
                Kl[(size_t)t * N + col] = (__bf16)(o - (float)h16);
            }
}

// =====================================================================
// Qe-proj split GEMM (f32-staging body), 32x128 tile, rows 0..63 only.
// Epilogue: rope (t<64 always here), emit Qeh/Qel bf16 split pair.
// =====================================================================
__device__ __forceinline__ void gemm_qesplit_body(const void* __restrict__ A,
                                                  const void* __restrict__ B,
                                                  __bf16* __restrict__ Qeh,
                                                  __bf16* __restrict__ Qel,
                                                  int N, bool f, int bm, int bn,
                                                  const void* __restrict__ fc,
                                                  const void* __restrict__ fs,
                                                  char* smem) {
    const int K = DIMM;
    float (*Asf)[36] = (float (*)[36])smem;              // 32*36*4 = 4608
    float (*Bsf)[36] = (float (*)[36])(smem + 4608);     // 128*36*4 = 18432
    int tid = threadIdx.x, wave = tid >> 6, lane = tid & 63;
    int quad = lane >> 4, l16 = lane & 15;
    int wn = wave * 32;
    const f32x4 z4 = {0.f, 0.f, 0.f, 0.f};
    f32x4 acc[2][2];
    for (int a = 0; a < 2; ++a) for (int b = 0; b < 2; ++b) acc[a][b] = z4;
    int arow = tid >> 3, acol = (tid & 7) * 4;
    for (int k0 = 0; k0 < K; k0 += 32) {
        {
            f32x4 va = load4(A, (size_t)(bm * 32 + arow) * K + k0 + acol, f);
            *(f32x4*)&Asf[arow][acol] = va;
        }
        for (int it = 0; it < 4; ++it) {
            int g = tid + it * 256;
            int krow = g >> 5, ng = (g & 31) * 4;
            f32x4 v = load4(B, (size_t)(k0 + krow) * N + bn * 128 + ng, f);
            Bsf[ng + 0][krow] = v[0];
            Bsf[ng + 1][krow] = v[1];
            Bsf[ng + 2][krow] = v[2];
            Bsf[ng + 3][krow] = v[3];
        }
        __syncthreads();
        bf16x8 ah[2], al[2], bh[2], bl[2];
        for (int mt = 0; mt < 2; ++mt) split8(&Asf[mt * 16 + l16][quad * 8], ah[mt], al[mt]);
        for (int nt = 0; nt < 2; ++nt) split8(&Bsf[wn + nt * 16 + l16][quad * 8], bh[nt], bl[nt]);
        for (int mt = 0; mt < 2; ++mt)
            for (int nt = 0; nt < 2; ++nt) {
                acc[mt][nt] = __builtin_amdgcn_mfma_f32_16x16x32_bf16(al[mt], bh[nt], acc[mt][nt], 0, 0, 0);
                acc[mt][nt] = __builtin_amdgcn_mfma_f32_16x16x32_bf16(ah[mt], bl[nt], acc[mt][nt], 0, 0, 0);
                acc[mt][nt] = __builtin_amdgcn_mfma_f32_16x16x32_bf16(ah[mt], bh[nt], acc[mt][nt], 0, 0, 0);
            }
        __syncthreads();
    }
    for (int mt = 0; mt < 2; ++mt)
        for (int nt = 0; nt < 2; ++nt)
#pragma unroll
            for (int r = 0; r < 4; ++r) {
                int col = bn * 128 + wn + nt * 16 + l16;
                int t = bm * 32 + mt * 16 + quad * 4 + r;
                float v = acc[mt][nt][r];
                float pv = __shfl_xor(v, 1);
                int j = (col & 63) >> 1;
                float c, s;
                cs_at(fc, fs, f, t, j, c, s);
                float o = (lane & 1) ? (pv * s + v * c) : (v * c - pv * s);
                __bf16 h16 = (__bf16)o;
                Qeh[(size_t)t * N + col] = h16;
                Qel[(size_t)t * N + col] = (__bf16)(o - (float)h16);
            }
}

// K-split (512 blocks) + Qe-split (32 blocks). grid 544.
__global__ __launch_bounds__(256) void split_dual_rope_k(const void* __restrict__ x,
                                                         const __bf16* __restrict__ Wtk_h,
                                                         const __bf16* __restrict__ Wtk_l,
                                                         __bf16* __restrict__ Kh,
                                                         __bf16* __restrict__ Kl,
                                                         const void* __restrict__ wq,
                                                         __bf16* __restrict__ Qeh,
                                                         __bf16* __restrict__ Qel,
                                                         const void* __restrict__ fc,
                                                         const void* __restrict__ fs,
                                                         const int* __restrict__ flag) {
    __shared__ __align__(16) char smem[41472];
    bool f = (*flag != 0);
    int bid = blockIdx.x;
    if (bid < 512) {
        gemm_ksplit_body(x, Wtk_h, Wtk_l, Kh, Kl, f, bid >> 2, bid & 3, fc, fs, smem);
    } else {
        int i = bid - 512;
        gemm_qesplit_body(x, wq, Qeh, Qel, 2048, f, i >> 4, i & 15, fc, fs, smem);
    }
}

// =====================================================================
// bf16 NT GEMM body (global_load_lds staging, linear [128][64] LDS).
// =====================================================================
__device__ __forceinline__ void gemm_nt_body(const __bf16* __restrict__ A,
                                             const __bf16* __restrict__ Bt,
                                             void* __restrict__ C, int N,
                                             int bm, int bn, bool f, int mode,
                                             const void* __restrict__ fc,
                                             const void* __restrict__ fs,
                                             char* smem) {
    const int K = DIMM;
    __bf16* As = (__bf16*)smem;
    __bf16* Bs = (__bf16*)(smem + 16384);
    int tid = threadIdx.x, wave = tid >> 6, lane = tid & 63;
    int quad = lane >> 4, l16 = lane & 15;
    int wm = (wave >> 1) * 64, wn = (wave & 1) * 64;
    const f32x4 z4 = {0.f, 0.f, 0.f, 0.f};
    f32x4 acc[4][4];
    for (int a = 0; a < 4; ++a) for (int b = 0; b < 4; ++b) acc[a][b] = z4;
    const __bf16* Ab = A  + (size_t)(bm * 128) * K;
    const __bf16* Bb = Bt + (size_t)(bn * 128) * K;
    for (int k0 = 0; k0 < K; k0 += 64) {
#pragma unroll
        for (int it = 0; it < 4; ++it) {
            int ci = it * 256 + tid;
            int row = ci >> 3, c8 = (ci & 7) * 8;
            gl_lds16(Ab + (size_t)row * K + k0 + c8, As + ci * 8);
            gl_lds16(Bb + (size_t)row * K + k0 + c8, Bs + ci * 8);
        }
        __syncthreads();
#pragma unroll
        for (int ks = 0; ks < 2; ++ks) {
            bf16x8 af[4], bfr[4];
#pragma unroll
            for (int mt = 0; mt < 4; ++mt)
                af[mt]  = *(const bf16x8*)&As[(wm + mt * 16 + l16) * 64 + ks * 32 + quad * 8];
#pragma unroll
            for (int nt = 0; nt < 4; ++nt)
                bfr[nt] = *(const bf16x8*)&Bs[(wn + nt * 16 + l16) * 64 + ks * 32 + quad * 8];
#pragma unroll
            for (int mt = 0; mt < 4; ++mt)
#pragma unroll
                for (int nt = 0; nt < 4; ++nt)
                    acc[mt][nt] = __builtin_amdgcn_mfma_f32_16x16x32_bf16(af[mt], bfr[nt], acc[mt][nt], 0, 0, 0);
        }
        __syncthreads();
    }
    if (mode == MODE_Q) {
        for (int mt = 0; mt < 4; ++mt)
            for (int nt = 0; nt < 4; ++nt)
#pragma unroll
                for (int r = 0; r < 4; ++r) {
                    int col = bn * 128 + wn + nt * 16 + l16;
                    int t = bm * 128 + wm + mt * 16 + quad * 4 + r;
                    float qv = (float)(__bf16)acc[mt][nt][r];
                    float pv = __shfl_xor(qv, 1);
                    int j = (col & 63) >> 1;
                    float c, s;
                    cs_at(fc, fs, f, t, j, c, s);
                    float o = (lane & 1) ? (pv * s + qv * c) : (qv * c - pv * s);
                    ((__bf16*)C)[(size_t)t * N + col] = (__bf16)o;
                }
    } else if (mode == MODE_O) {
        bool f32o = f;
        for (int mt = 0; mt < 4; ++mt)
            for (int nt = 0; nt < 4; ++nt) {
                int rowb = bm * 128 + wm + mt * 16 + quad * 4;
                int col = bn * 128 + wn + nt * 16 + l16;
                if (f32o) {
                    for (int r = 0; r < 4; ++r)
                        ((float*)C)[(size_t)(rowb + r) * N + col] = acc[mt][nt][r];
                } else {
                    for (int r = 0; r < 4; ++r)
                        ((__bf16*)C)[(size_t)(rowb + r) * N + col] = (__bf16)acc[mt][nt][r];
                }
            }
    } else {
        for (int mt = 0; mt < 4; ++mt)
            for (int nt = 0; nt < 4; ++nt) {
                int rowb = bm * 128 + wm + mt * 16 + quad * 4;
                int col = bn * 128 + wn + nt * 16 + l16;
                for (int r = 0; r < 4; ++r)
                    ((__bf16*)C)[(size_t)(rowb + r) * N + col] = (__bf16)acc[mt][nt][r];
            }
    }
}

// Q-proj only (rope epilogue). grid (32,16).
__global__ __launch_bounds__(256) void gemm_q_k(const __bf16* __restrict__ xbf,
                                                const __bf16* __restrict__ Wtq,
                                                __bf16* __restrict__ Qb,
                                                const void* __restrict__ fc,
                                                const void* __restrict__ fs,
                                                const int* __restrict__ flag) {
    __shared__ __align__(16) char smem[32768];
    bool f = (*flag != 0);
    gemm_nt_body(xbf, Wtq, Qb, 2048, blockIdx.x, blockIdx.y, f, MODE_Q, fc, fs, smem);
}

// Output projection: AO @ Wto (NT), f32 store if f32 inputs.
__global__ __launch_bounds__(256) void gemm_o_k(const __bf16* __restrict__ A,
                                                const __bf16* __restrict__ Bt,
                                                void* __restrict__ C,
                                                const int* __restrict__ flag) {
    __shared__ __align__(16) char smem[32768];
    bool f = (*flag != 0);
    gemm_nt_body(A, Bt, C, 2048, blockIdx.x, blockIdx.y, f, MODE_O, nullptr, nullptr, smem);
}

// =====================================================================
// Estimation partials. grid (32 heads, 8). Fragments loaded DIRECTLY
// from pre-split Kh/Kl/Qeh/Qel (bit-identical to the old split8(f32)).
// Also zeroes its head/slice of diag.
// =====================================================================
__global__ __launch_bounds__(256) void est_part_k(const __bf16* __restrict__ Qeh,
                                                  const __bf16* __restrict__ Qel,
                                                  const __bf16* __restrict__ Kh,
                                                  const __bf16* __restrict__ Kl,
                                                  float* __restrict__ pm,
                                                  float* __restrict__ ps,
                                                  float* __restrict__ diag) {
    int h = blockIdx.x, sl = blockIdx.y;
    int tid = threadIdx.x, wave = tid >> 6, lane = tid & 63;
    int quad = lane >> 4, l16 = lane & 15;
    for (int i = tid; i < 512; i += 256) diag[h * SEQ + sl * 512 + i] = 0.f;
    __shared__ float Ml[64];
    __shared__ float pA[4][64];
    bf16x8 qh[4][2], ql[4][2];
    for (int mt = 0; mt < 4; ++mt)
        for (int kc = 0; kc < 2; ++kc) {
            size_t qo = (size_t)(mt * 16 + l16) * DIMM + h * HD + kc * 32 + quad * 8;
            qh[mt][kc] = *(const bf16x8*)(Qeh + qo);
            ql[mt][kc] = *(const bf16x8*)(Qel + qo);
        }
    int kvoff = (h >> 2) * HD;
    float pmax[4][4];
    for (int mt = 0; mt < 4; ++mt) for (int r = 0; r < 4; ++r) pmax[mt][r] = -3.0e38f;
    for (int jb = wave; jb < 8; jb += 4)
        for (int c = 0; c < 4; ++c) {
            int j0 = sl * 512 + jb * 64 + c * 16;
            size_t ko = (size_t)(j0 + l16) * (NKV * HD) + kvoff + quad * 8;
            bf16x8 kh0 = *(const bf16x8*)(Kh + ko);
            bf16x8 kl0 = *(const bf16x8*)(Kl + ko);
            bf16x8 kh1 = *(const bf16x8*)(Kh + ko + 32);
            bf16x8 kl1 = *(const bf16x8*)(Kl + ko + 32);
            int j = j0 + l16;
            for (int mt = 0; mt < 4; ++mt) {
                f32x4 acc = {0.f, 0.f, 0.f, 0.f};
                acc = __builtin_amdgcn_mfma_f32_16x16x32_bf16(ql[mt][0], kh0, acc, 0, 0, 0);
                acc = __builtin_amdgcn_mfma_f32_16x16x32_bf16(qh[mt][0], kl0, acc, 0, 0, 0);
                acc = __builtin_amdgcn_mfma_f32_16x16x32_bf16(qh[mt][0], kh0, acc, 0, 0, 0);
                acc = __builtin_amdgcn_mfma_f32_16x16x32_bf16(ql[mt][1], kh1, acc, 0, 0, 0);
                acc = __builtin_amdgcn_mfma_f32_16x16x32_bf16(qh[mt][1], kl1, acc, 0, 0, 0);
                acc = __builtin_amdgcn_mfma_f32_16x16x32_bf16(qh[mt][1], kh1, acc, 0, 0, 0);
                for (int r = 0; r < 4; ++r) {
                    int q = mt * 16 + quad * 4 + r;
                    float sv = acc[r] * 0.125f;
                    if (j >= SEQ - 64 && q < j - (SEQ - 64)) sv = -1e30f;
                    pmax[mt][r] = fmaxf(pmax[mt][r], sv);
                }
            }
        }
    for (int mt = 0; mt < 4; ++mt)
        for (int r = 0; r < 4; ++r)
            for (int m2 = 1; m2 < 16; m2 <<= 1)
                pmax[mt][r] = fmaxf(pmax[mt][r], __shfl_xor(pmax[mt][r], m2));
    if (l16 == 0)
        for (int mt = 0; mt < 4; ++mt)
            for (int r = 0; r < 4; ++r)
                pA[wave][mt * 16 + quad * 4 + r] = pmax[mt][r];
    __syncthreads();
    if (tid < 64)
        Ml[tid] = fmaxf(fmaxf(pA[0][tid], pA[1][tid]), fmaxf(pA[2][tid], pA[3][tid]));
    __syncthreads();
    float mreg[4][4];
    for (int mt = 0; mt < 4; ++mt)
        for (int r = 0; r < 4; ++r)
            mreg[mt][r] = Ml[mt * 16 + quad * 4 + r];
    float psum[4][4];
    for (int mt = 0; mt < 4; ++mt) for (int r = 0; r < 4; ++r) psum[mt][r] = 0.f;
    for (int jb = wave; jb < 8; jb += 4)
        for (int c = 0; c < 4; ++c) {
            int j0 = sl * 512 + jb * 64 + c * 16;
            size_t ko = (size_t)(j0 + l16) * (NKV * HD) + kvoff + quad * 8;
            bf16x8 kh0 = *(const bf16x8*)(Kh + ko);
            bf16x8 kl0 = *(const bf16x8*)(Kl + ko);
            bf16x8 kh1 = *(const bf16x8*)(Kh + ko + 32);
            bf16x8 kl1 = *(const bf16x8*)(Kl + ko + 32);
            int j = j0 + l16;
            for (int mt = 0; mt < 4; ++mt) {
                f32x4 acc = {0.f, 0.f, 0.f, 0.f};
                acc = __builtin_amdgcn_mfma_f32_16x16x32_bf16(ql[mt][0], kh0, acc, 0, 0, 0);
                acc = __builtin_amdgcn_mfma_f32_16x16x32_bf16(qh[mt][0], kl0, acc, 0, 0, 0);
                acc = __builtin_amdgcn_mfma_f32_16x16x32_bf16(qh[mt][0], kh0, acc, 0, 0, 0);
                acc = __builtin_amdgcn_mfma_f32_16x16x32_bf16(ql[mt][1], kh1, acc, 0, 0, 0);
                acc = __builtin_amdgcn_mfma_f32_16x16x32_bf16(qh[mt][1], kl1, acc, 0, 0, 0);
                acc = __builtin_amdgcn_mfma_f32_16x16x32_bf16(qh[mt][1], kh1, acc, 0, 0, 0);
                for (int r = 0; r < 4; ++r) {
                    int q = mt * 16 + quad * 4 + r;
                    float sv = acc[r] * 0.125f;
                    if (j >= SEQ - 64 && q < j - (SEQ - 64)) sv = -1e30f;
                    psum[mt][r] += __expf(sv - mreg[mt][r]);
                }
            }
        }
    for (int mt = 0; mt < 4; ++mt)
        for (int r = 0; r < 4; ++r)
            for (int m2 = 1; m2 < 16; m2 <<= 1)
                psum[mt][r] += __shfl_xor(psum[mt][r], m2);
    if (l16 == 0)
        for (int mt = 0; mt < 4; ++mt)
            for (int r = 0; r < 4; ++r)
                pA[wave][mt * 16 + quad * 4 + r] = psum[mt][r];
    __syncthreads();
    if (tid < 64) {
        pm[(h * 8 + sl) * 64 + tid] = Ml[tid];
        ps[(h * 8 + sl) * 64 + tid] = pA[0][tid] + pA[1][tid] + pA[2][tid] + pA[3][tid];
    }
}

// =====================================================================
// vertical/diag accumulation. grid (32,32). Pre-split fragment loads;
// rmax/rsum computed inline from pm/ps.
// =====================================================================
__global__ __launch_bounds__(256) void vert_diag_k(const __bf16* __restrict__ Qeh,
                                                   const __bf16* __restrict__ Qel,
                                                   const __bf16* __restrict__ Kh,
                                                   const __bf16* __restrict__ Kl,
                                                   const float* __restrict__ pm,
                                                   const float* __restrict__ ps,
                                                   float* __restrict__ vert,
                                                   float* __restrict__ diag) {
    int h = blockIdx.x, jb = blockIdx.y;
    int tid = threadIdx.x, wave = tid >> 6, lane = tid & 63;
    int quad = lane >> 4, l16 = lane & 15;
    __shared__ float P[64][132];
    __shared__ float dloc[192];
    __shared__ float rm_l[64], rs_l[64];
    for (int i = tid; i < 192; i += 256) dloc[i] = 0.f;
    if (tid < 64) {
        float M = -3.0e38f;
        for (int sl = 0; sl < 8; ++sl) M = fmaxf(M, pm[(h * 8 + sl) * 64 + tid]);
        float S = 0.f;
        for (int sl = 0; sl < 8; ++sl)
            S += ps[(h * 8 + sl) * 64 + tid] * __expf(pm[(h * 8 + sl) * 64 + tid] - M);
        rm_l[tid] = M;
        rs_l[tid] = S;
    }
    bf16x8 qh[4][2], ql[4][2];
    for (int mt = 0; mt < 4; ++mt)
        for (int kc = 0; kc < 2; ++kc) {
            size_t qo = (size_t)(mt * 16 + l16) * DIMM + h * HD + kc * 32 + quad * 8;
            qh[mt][kc] = *(const bf16x8*)(Qeh + qo);
            ql[mt][kc] = *(const bf16x8*)(Qel + qo);
        }
    __syncthreads();
    float rm[4][4], rs[4][4];
    for (int mt = 0; mt < 4; ++mt)
        for (int r = 0; r < 4; ++r) {
            int q = mt * 16 + quad * 4 + r;
            rm[mt][r] = rm_l[q];
            rs[mt][r] = rs_l[q];
        }
    int kvoff = (h >> 2) * HD;
    for (int c = 0; c < 2; ++c) {
        int jl0 = wave * 32 + c * 16;
        int j0 = jb * 128 + jl0;
        size_t ko = (size_t)(j0 + l16) * (NKV * HD) + kvoff + quad * 8;
        bf16x8 kh0 = *(const bf16x8*)(Kh + ko);
        bf16x8 kl0 = *(const bf16x8*)(Kl + ko);
        bf16x8 kh1 = *(const bf16x8*)(Kh + ko + 32);
        bf16x8 kl1 = *(const bf16x8*)(Kl + ko + 32);
        int j = j0 + l16;
        for (int mt = 0; mt < 4; ++mt) {
            f32x4 acc = {0.f, 0.f, 0.f, 0.f};
            acc = __builtin_amdgcn_mfma_f32_16x16x32_bf16(ql[mt][0], kh0, acc, 0, 0, 0);
            acc = __builtin_amdgcn_mfma_f32_16x16x32_bf16(qh[mt][0], kl0, acc, 0, 0, 0);
            acc = __builtin_amdgcn_mfma_f32_16x16x32_bf16(qh[mt][0], kh0, acc, 0, 0, 0);
            acc = __builtin_amdgcn_mfma_f32_16x16x32_bf16(ql[mt][1], kh1, acc, 0, 0, 0);
            acc = __builtin_amdgcn_mfma_f32_16x16x32_bf16(qh[mt][1], kl1, acc, 0, 0, 0);
            acc = __builtin_amdgcn_mfma_f32_16x16x32_bf16(qh[mt][1], kh1, acc, 0, 0, 0);
            for (int r = 0; r < 4; ++r) {
                int q = mt * 16 + quad * 4 + r;
                float sv = acc[r] * 0.125f;
                if (j >= SEQ - 64 && q < j - (SEQ - 64)) sv = -1e30f;
                P[q][jl0 + l16] = __expf(sv - rm[mt][r]) / rs[mt][r];
            }
        }
    }
    __syncthreads();
    if (tid < 128) {
        float vacc = 0.f;
        for (int q = 0; q < 64; ++q) {
            float pb = P[q][tid];
            vacc += pb;
            if (jb * 128 + tid + 63 - q < SEQ) atomicAdd(&dloc[tid + 63 - q], pb);
        }
        vert[h * SEQ + jb * 128 + tid] = vacc;
    }
    __syncthreads();
    for (int i = tid; i < 192; i += 256) {
        int g = jb * 128 + i;
        if (g < SEQ) atomicAdd(&diag[h * SEQ + g], dloc[i]);
    }
}

// =====================================================================
// Merged: per-head top-k (32 blocks) + V-proj (128 blocks). grid 160.
// V-proj reads xbf/Wtv, writes Vb (over dead Kl) — disjoint from topk.
// =====================================================================
__global__ __launch_bounds__(256) void topk_vproj_k(const float* __restrict__ vert,
                                                    const float* __restrict__ diag,
                                                    int* __restrict__ skeys,
                                                    const __bf16* __restrict__ xbf,
                                                    const __bf16* __restrict__ Wtv,
                                                    __bf16* __restrict__ Vb,
                                                    const int* __restrict__ flag) {
    if (blockIdx.x >= 32) {
        __shared__ __align__(16) char smem[32768];
        bool f = (*flag != 0);
        int id = blockIdx.x - 32;
        gemm_nt_body(xbf, Wtv, Vb, 512, id >> 2, id & 3, f, MODE_V, nullptr, nullptr, smem);
        return;
    }
    __shared__ int cnt[4096];
    __shared__ int hist4[4][256];
    __shared__ int scanb[256];
    __shared__ int B_sh, kk_sh;
    int h = blockIdx.x, tid = threadIdx.x, wave = tid >> 6;
    for (int i = tid; i < 4096; i += 256) cnt[i] = 0;
    __syncthreads();
    for (int selp = 0; selp < 2; ++selp) {
        const float* vals = (selp == 0 ? vert : diag) + h * SEQ;
        int k = (selp == 0) ? 300 : 800;
        bool flip = (selp == 1);
        unsigned bits[16];
        for (int g = 0; g < 4; ++g) {
            f32x4 v = *(const f32x4*)(vals + tid * 16 + g * 4);
            for (int e = 0; e < 4; ++e) bits[g * 4 + e] = __float_as_uint(v[e]);
        }
        unsigned prefix = 0;
        int kk = k;
        for (int pass = 0; pass < 4; ++pass) {
            int sh = 8 * (3 - pass);
            for (int w = 0; w < 4; ++w) hist4[w][tid] = 0;
            __syncthreads();
            for (int e = 0; e < 16; ++e) {
                unsigned b = bits[e];
                bool in = (pass == 0) || ((b >> (sh + 8)) == prefix);
                if (in) atomicAdd(&hist4[wave][(b >> sh) & 255], 1);
            }
            __syncthreads();
            scanb[tid] = hist4[0][tid] + hist4[1][tid] + hist4[2][tid] + hist4[3][tid];
            __syncthreads();
            for (int off = 1; off < 256; off <<= 1) {
                int v = (tid + off < 256) ? scanb[tid + off] : 0;
                __syncthreads();
                scanb[tid] += v;
                __syncthreads();
            }
            int sufNext = (tid < 255) ? scanb[tid + 1] : 0;
            if (scanb[tid] >= kk && sufNext < kk) { B_sh = tid; kk_sh = kk - sufNext; }
            __syncthreads();
            prefix = (prefix << 8) | (unsigned)B_sh;
            kk = kk_sh;
            __syncthreads();
        }
        int localEq = 0;
        for (int e = 0; e < 16; ++e) {
            unsigned b = bits[e];
            if (b > prefix) {
                int idx = tid * 16 + e;
                atomicAdd(&cnt[flip ? (4095 - idx) : idx], 1);
            } else if (b == prefix) ++localEq;
        }
        scanb[tid] = localEq;
        __syncthreads();
        for (int off = 1; off < 256; off <<= 1) {
            int v = (tid >= off) ? scanb[tid - off] : 0;
            __syncthreads();
            scanb[tid] += v;
            __syncthreads();
        }
        int eqOff = scanb[tid] - localEq;
        int taken = 0;
        for (int e = 0; e < 16; ++e) {
            unsigned b = bits[e];
            if (b == prefix) {
                if (eqOff + taken < kk) {
                    int idx = tid * 16 + e;
                    atomicAdd(&cnt[flip ? (4095 - idx) : idx], 1);
                }
                ++taken;
            }
        }
        __syncthreads();
    }
    int base = tid * 16;
    int loc[16];
    int s = 0;
    for (int e = 0; e < 16; ++e) { loc[e] = s; s += cnt[base + e]; }
    scanb[tid] = s;
    __syncthreads();
    for (int off = 1; off < 256; off <<= 1) {
        int v = (tid >= off) ? scanb[tid - off] : 0;
        __syncthreads();
        scanb[tid] += v;
        __syncthreads();
    }
    int chunkExcl = scanb[tid] - s;
    int* out = skeys + h * NSPP;
    for (int e = 0; e < 16; ++e) {
        int c = cnt[base + e];
        int pos = chunkExcl + loc[e];
        for (int r = 0; r < c; ++r) out[pos + r] = base + e;
    }
    for (int i = NSP + tid; i < NSPP; i += 256) out[i] = 0x7fffffff;
}

// =====================================================================
// Merged: gather sparse K/V (576 blocks) + wo transpose (4096 blocks).
// Kh doubles as Kb (identical bits).
// =====================================================================
__global__ __launch_bounds__(256) void gather_wot_k(const __bf16* __restrict__ Kb,
                                                    const __bf16* __restrict__ Vb,
                                                    const int* __restrict__ skeys,
                                                    __bf16* __restrict__ Ksp,
                                                    __bf16* __restrict__ VspT,
                                                    const void* __restrict__ wo,
                                                    __bf16* __restrict__ Wto,
                                                    const int* __restrict__ flag) {
    int bid = blockIdx.x;
    if (bid >= 576) {
        bool f = (*flag != 0);
        int id = bid - 576;
        transpose_body(wo, Wto, 2048, 2048, f, (id >> 6) * 32, (id & 63) * 32);
        return;
    }
    int h = bid / 18, jb = bid % 18;
    __shared__ __bf16 tile[64][72];
    int tid = threadIdx.x;
    int jl = tid >> 2, d0 = (tid & 3) * 16;
    int j = jb * 64 + jl;
    int key = skeys[h * NSPP + j];
    int kv = (h >> 2) * HD;
    const bf16x8 z = {};
    bf16x8 k0v = z, k1v = z, v0v = z, v1v = z;
    if ((unsigned)key < SEQ) {
        const __bf16* ks = Kb + (size_t)key * (NKV * HD) + kv + d0;
        const __bf16* vs = Vb + (size_t)key * (NKV * HD) + kv + d0;
        k0v = *(const bf16x8*)ks; k1v = *(const bf16x8*)(ks + 8);
        v0v = *(const bf16x8*)vs; v1v = *(const bf16x8*)(vs + 8);
    }
    __bf16* kd = Ksp + ((size_t)h * NSPP + j) * HD + d0;
    *(bf16x8*)kd = k0v;
    *(bf16x8*)(kd + 8) = k1v;
    *(bf16x8*)&tile[jl][d0] = v0v;
    *(bf16x8*)&tile[jl][d0 + 8] = v1v;
    __syncthreads();
    int d = tid >> 2, jl0 = (tid & 3) * 16;
    bf16x8 o0, o1;
    for (int e = 0; e < 8; ++e) { o0[e] = tile[jl0 + e][d]; o1[e] = tile[jl0 + 8 + e][d]; }
    __bf16* vt = VspT + ((size_t)h * HD + d) * NSPP + jb * 64 + jl0;
    *(bf16x8*)vt = o0;
    *(bf16x8*)(vt + 8) = o1;
}

// =====================================================================
// Sparse attention: grid (64,32), 512 thr. 3-phase LDS-score, QBLK=64.
// AO aliases Qb in-place (block-local RAW only).
// =====================================================================
__global__ __launch_bounds__(512) void sparse_attn_k(const __bf16* Qb,
                                                     const __bf16* __restrict__ Ksp,
                                                     const __bf16* __restrict__ VspT,
                                                     const int* __restrict__ skeys,
                                                     __bf16* AO) {
    int qb = blockIdx.x, h = blockIdx.y;
    int tid = threadIdx.x, wave = tid >> 6, lane = tid & 63;
    int quad = lane >> 4, l16 = lane & 15;
    __shared__ __bf16 sc[64][1160];
    __shared__ float rsm[64];
    int t0 = qb * 64;
    bf16x8 aq[4][2];
#pragma unroll
    for (int qs = 0; qs < 4; ++qs)
#pragma unroll
        for (int kc = 0; kc < 2; ++kc)
            aq[qs][kc] = *(const bf16x8*)(Qb + (size_t)(t0 + qs * 16 + l16) * DIMM + h * HD + kc * 32 + quad * 8);
    const __bf16* Kh2 = Ksp + (size_t)h * NSPP * HD;
    const int* sk = skeys + h * NSPP;
#pragma unroll
    for (int c = 0; c < 9; ++c) {
        int j0 = wave * 144 + c * 16;
        const __bf16* kp = Kh2 + (size_t)(j0 + l16) * HD + quad * 8;
        bf16x8 b0 = *(const bf16x8*)kp;
        bf16x8 b1 = *(const bf16x8*)(kp + 32);
        int j = j0 + l16;
        int key = sk[j];
#pragma unroll
        for (int qs = 0; qs < 4; ++qs) {
            f32x4 acc = {0.f, 0.f, 0.f, 0.f};
            acc = __builtin_amdgcn_mfma_f32_16x16x32_bf16(aq[qs][0], b0, acc, 0, 0, 0);
            acc = __builtin_amdgcn_mfma_f32_16x16x32_bf16(aq[qs][1], b1, acc, 0, 0, 0);
            int qg = t0 + qs * 16 + quad * 4;
#pragma unroll
            for (int r = 0; r < 4; ++r) {
                float sv = acc[r] * 0.125f;
                if (key > qg + r) sv = -1e30f;
                sc[qs * 16 + quad * 4 + r][j] = (__bf16)sv;
            }
        }
    }
    __syncthreads();
    {
        int row = tid >> 3, sub = tid & 7;
        int c0 = sub * 144;
        float mx = -3.0e38f;
        for (int i = 0; i < 18; ++i) {
            bf16x8 v = *(const bf16x8*)&sc[row][c0 + i * 8];
            for (int e = 0; e < 8; ++e) mx = fmaxf(mx, (float)v[e]);
        }
        for (int m2 = 1; m2 < 8; m2 <<= 1) mx = fmaxf(mx, __shfl_xor(mx, m2, 8));
        float sm = 0.f;
        for (int i = 0; i < 18; ++i) {
            int cb = c0 + i * 8;
            bf16x8 v = *(const bf16x8*)&sc[row][cb];
            bf16x8 pw;
            for (int e = 0; e < 8; ++e) {
                float pv = 0.f;
                if (cb + e < NSP) { pv = __expf((float)v[e] - mx); sm += pv; }
                pw[e] = (__bf16)pv;
            }
            *(bf16x8*)&sc[row][cb] = pw;
        }
        for (int m2 = 1; m2 < 8; m2 <<= 1) sm += __shfl_xor(sm, m2, 8);
        if (sub == 0) rsm[row] = sm;
    }
    __syncthreads();
    int qs = wave >> 1, dh = wave & 1;
    const f32x4 z4 = {0.f, 0.f, 0.f, 0.f};
    f32x4 o0 = z4, o1 = z4;
    const __bf16* Vh = VspT + ((size_t)h * HD + dh * 32) * NSPP;
#pragma unroll 4
    for (int c = 0; c < 36; ++c) {
        int kb = c * 32;
        bf16x8 pa = *(const bf16x8*)&sc[qs * 16 + l16][kb + quad * 8];
        bf16x8 v0 = *(const bf16x8*)(Vh + (size_t)l16 * NSPP + kb + quad * 8);
        bf16x8 v1 = *(const bf16x8*)(Vh + (size_t)(16 + l16) * NSPP + kb + quad * 8);
        o0 = __builtin_amdgcn_mfma_f32_16x16x32_bf16(pa, v0, o0, 0, 0, 0);
        o1 = __builtin_amdgcn_mfma_f32_16x16x32_bf16(pa, v1, o1, 0, 0, 0);
    }
#pragma unroll
    for (int r = 0; r < 4; ++r) {
        int ql = qs * 16 + quad * 4 + r;
        float inv = 1.f / rsm[ql];
        size_t base = (size_t)(t0 + ql) * DIMM + h * HD + dh * 32;
        AO[base + l16]      = (__bf16)(o0[r] * inv);
        AO[base + 16 + l16] = (__bf16)(o1[r] * inv);
    }
}

// =====================================================================
// Launch. 10 dispatches. Liveness map (step = dispatch order):
//  1 detect  2 convert+wkT+wqT+wvT  3 split_dual  4 est  5 vert
//  6 topk+vproj  7 gemm_q  8 gather+woT  9 attn  10 gemm_o
//   Wtk_h 0..2,097,152        [2->3]
//   Wtk_l 2,097,152..4,194,304[2->3]
//   Qeh   4,194,304..4,456,448[3->5]   (under Qb; Qb written step 7 - OK)
//   Qel   4,456,448..4,718,592[3->5]
//   pm    4,718,592..4,784,128[4->5]
//   ps    4,784,128..4,849,664[4->5]
//   vert  4,849,664..5,373,952[5->6]
//   diag  5,373,952..5,898,240[4->6]
//   Qb    0..16,777,216       [7->10]  (attn in-place at 9)
//   Kh    16,777,216..20,971,520 [3->8] (= Kb for gather)
//   Kl    20,971,520..25,165,824 [3->5]; Vb same region [6->8] (seq OK)
//   xbf   25,165,824..41,943,040 [2->7]; Ksp 25.17M..29.88M,
//         VspT 29.88M..34.6M [8->9] (xbf dead after 7)
//   Wtq   41,943,040..50,331,648 [2->7]; Wto same [8->10] (Wtq dead)
//   Wtv   50,331,648..52,428,800 [2->6]
//   skeys 52,445,184 [6->9] (outside Qb: attn in-place write at 9)
//   flag  52,592,640 [1->]
// =====================================================================
extern "C" void kernel_launch(void* const* d_in, const int* in_sizes, int n_in,
                              void* d_out, int out_size, void* d_ws, size_t ws_size,
                              hipStream_t stream) {
    const void* x  = d_in[0];
    const void* fc = d_in[1];
    const void* fs = d_in[2];
    const void* wq = d_in[3];
    const void* wk = d_in[4];
    const void* wv = d_in[5];
    const void* wo = d_in[6];
    char* ws = (char*)d_ws;

    __bf16* Wtk_h= (__bf16*)(ws + 0);
    __bf16* Wtk_l= (__bf16*)(ws + 2097152);
    __bf16* Qeh  = (__bf16*)(ws + 4194304);
    __bf16* Qel  = (__bf16*)(ws + 4456448);
    float*  pm   = (float*)(ws + 4718592);
    float*  ps   = (float*)(ws + 4784128);
    float*  vert = (float*)(ws + 4849664);
    float*  diag = (float*)(ws + 5373952);
    __bf16* Qb   = (__bf16*)(ws + 0);          // step 7+; also AO in-place
    __bf16* Kh   = (__bf16*)(ws + 16777216);   // = Kb
    __bf16* Kl   = (__bf16*)(ws + 20971520);
    __bf16* Vb   = (__bf16*)(ws + 20971520);   // after Kl dead
    __bf16* xbf  = (__bf16*)(ws + 25165824);
    __bf16* Ksp  = (__bf16*)(ws + 25165824);   // after xbf dead
    __bf16* VspT = (__bf16*)(ws + 29884416);
    __bf16* Wtq  = (__bf16*)(ws + 41943040);
    __bf16* Wto  = (__bf16*)(ws + 41943040);   // after Wtq dead
    __bf16* Wtv  = (__bf16*)(ws + 50331648);
    int*    skeys= (int*)(ws + 52445184);
    int*    flag = (int*)(ws + 52592640);

    dim3 b256(256);
    detect_k<<<1, b256, 0, stream>>>(x, flag);
    // x -> xbf + ALL weight transposes (wk split, wq, wv)
    convert_all_k<<<10240, b256, 0, stream>>>(x, xbf, wk, Wtk_h, Wtk_l,
                                              wq, Wtq, wv, Wtv, flag);
    // selection-path projections: K (pre-split B -> Kh/Kl) + Qe (-> Qeh/Qel)
    split_dual_rope_k<<<544, b256, 0, stream>>>(x, Wtk_h, Wtk_l, Kh, Kl,
                                                wq, Qeh, Qel, fc, fs, flag);
    est_part_k<<<dim3(32, 8), b256, 0, stream>>>(Qeh, Qel, Kh, Kl, pm, ps, diag);
    vert_diag_k<<<dim3(32, 32), b256, 0, stream>>>(Qeh, Qel, Kh, Kl, pm, ps, vert, diag);
    // topk + V-proj ride together (Kl dead -> Vb reuses its region)
    topk_vproj_k<<<160, b256, 0, stream>>>(vert, diag, skeys, xbf, Wtv, Vb, flag);
    // Q-proj (rope fused)
    gemm_q_k<<<dim3(32, 16), b256, 0, stream>>>(xbf, Wtq, Qb, fc, fs, flag);
    // gather sparse K/V (Kb == Kh) + wo transpose
    gather_wot_k<<<4672, b256, 0, stream>>>(Kh, Vb, skeys, Ksp, VspT, wo, Wto, flag);
    // sparse attention (in-place Qb -> AO)
    sparse_attn_k<<<dim3(64, 32), dim3(512), 0, stream>>>(Qb, Ksp, VspT, skeys, Qb);
    // output projection
    gemm_o_k<<<dim3(32, 16), b256, 0, stream>>>(Qb, Wto, d_out, flag);
}